// Round 1
// baseline (206.895 us; speedup 1.0000x reference)
//
#include <hip/hip_runtime.h>
#include <math.h>

#define N 4096
#define H 256
#define LAYERS 3
#define CAP 128
#define NPB 16

// ---------- helpers ----------
__device__ __forceinline__ float block_reduce_sum(float v, float* sm) {
    int tid = threadIdx.x;
    sm[tid] = v;
    __syncthreads();
    for (int s = 128; s > 0; s >>= 1) {
        if (tid < s) sm[tid] += sm[tid + s];
        __syncthreads();
    }
    float r = sm[0];
    __syncthreads();
    return r;
}

// ---------- edge-list construction ----------
__global__ void k_init_edges(int* __restrict__ cnt, int* __restrict__ edges) {
    int j = blockIdx.x * blockDim.x + threadIdx.x;
    if (j < N) {
        cnt[j] = 1;              // self-loop always present (set after masking in ref)
        edges[j * CAP] = j;
    }
}

__global__ void k_build_edges(const float* __restrict__ adj, const int* __restrict__ mask,
                              int* __restrict__ cnt, int* __restrict__ edges) {
    int i = blockIdx.x;                 // source row
    if (!mask[i]) return;
    const float* row = adj + (size_t)i * N;
    for (int j = threadIdx.x; j < N; j += blockDim.x) {
        if (j != i && row[j] != 0.0f && mask[j]) {
            int slot = atomicAdd(&cnt[j], 1);
            if (slot < CAP) edges[j * CAP + slot] = i;
        }
    }
}

// ---------- embedding: x = (in @ W1 + b1) @ W2 + b2 ----------
__global__ void k_embed(const float* __restrict__ arrival, const float* __restrict__ departure,
                        const float* __restrict__ hard,
                        const float* __restrict__ W1, const float* __restrict__ b1,
                        const float* __restrict__ W2, const float* __restrict__ b2,
                        const int* __restrict__ t_ts,
                        float* __restrict__ x) {
    __shared__ float t_lds[NPB][H];
    int tid = threadIdx.x;
    int base = blockIdx.x * NPB;
    float ts = (float)t_ts[0];
    for (int idx = tid; idx < NPB * H; idx += 256) {
        int p = idx >> 8, hh = idx & (H - 1);
        int n = base + p;
        float den = departure[n] - arrival[n];
        if (den == 0.f) den = 1.f;
        float prog = (ts - arrival[n]) / den;
        t_lds[p][hh] = prog * W1[hh] + hard[n] * W1[H + hh] + b1[hh];
    }
    __syncthreads();
    float acc[NPB];
#pragma unroll
    for (int p = 0; p < NPB; ++p) acc[p] = 0.f;
    for (int hh = 0; hh < H; ++hh) {
        float w = W2[hh * H + tid];
#pragma unroll
        for (int p = 0; p < NPB; ++p) acc[p] += t_lds[p][hh] * w;
    }
#pragma unroll
    for (int p = 0; p < NPB; ++p)
        x[(size_t)(base + p) * H + tid] = acc[p] + b2[tid];
}

// ---------- hw = h_in @ W ----------
__global__ void k_matmul(const float* __restrict__ hin, const float* __restrict__ W,
                         float* __restrict__ hw) {
    __shared__ float t_lds[NPB][H];
    int tid = threadIdx.x;
    int base = blockIdx.x * NPB;
    for (int idx = tid; idx < NPB * H; idx += 256) {
        int p = idx >> 8, hh = idx & (H - 1);
        t_lds[p][hh] = hin[(size_t)(base + p) * H + hh];
    }
    __syncthreads();
    float acc[NPB];
#pragma unroll
    for (int p = 0; p < NPB; ++p) acc[p] = 0.f;
    for (int hh = 0; hh < H; ++hh) {
        float w = W[hh * H + tid];
#pragma unroll
        for (int p = 0; p < NPB; ++p) acc[p] += t_lds[p][hh] * w;
    }
#pragma unroll
    for (int p = 0; p < NPB; ++p)
        hw[(size_t)(base + p) * H + tid] = acc[p];
}

// ---------- per-node attention scores a_s = hw@asrc, a_d = hw@adst ----------
__global__ void k_scores(const float* __restrict__ hw, const float* __restrict__ asrc,
                         const float* __restrict__ adst,
                         float* __restrict__ a_s, float* __restrict__ a_d) {
    __shared__ float sm[256];
    int n = blockIdx.x, tid = threadIdx.x;
    float v = hw[(size_t)n * H + tid];
    float s1 = block_reduce_sum(v * asrc[tid], sm);
    float s2 = block_reduce_sum(v * adst[tid], sm);
    if (tid == 0) { a_s[n] = s1; a_d[n] = s2; }
}

// ---------- sparse softmax-aggregate: h_out[j] = sum_i alpha[i,j] hw[i] + bias ----------
__global__ void k_aggregate(const float* __restrict__ hw, const float* __restrict__ a_s,
                            const float* __restrict__ a_d, const int* __restrict__ cnt,
                            const int* __restrict__ edges, const float* __restrict__ bias,
                            float* __restrict__ hout, int do_relu) {
    __shared__ float red[256];
    __shared__ float w_lds[CAP];
    __shared__ int   i_lds[CAP];
    int j = blockIdx.x, tid = threadIdx.x;
    int c = cnt[j];
    if (c > CAP) c = CAP;
    float e = -INFINITY;
    if (tid < c) {
        int i = edges[j * CAP + tid];
        i_lds[tid] = i;
        float v = a_s[i] + a_d[j];
        e = (v > 0.f) ? v : 0.2f * v;   // leaky_relu(., 0.2)
    }
    // max over edges
    red[tid] = e;
    __syncthreads();
    for (int s = 128; s > 0; s >>= 1) {
        if (tid < s) red[tid] = fmaxf(red[tid], red[tid + s]);
        __syncthreads();
    }
    float m = red[0];
    __syncthreads();
    float w = 0.f;
    if (tid < c) { w = __expf(e - m); w_lds[tid] = w; }
    red[tid] = w;
    __syncthreads();
    for (int s = 128; s > 0; s >>= 1) {
        if (tid < s) red[tid] += red[tid + s];
        __syncthreads();
    }
    float inv = 1.f / red[0];
    __syncthreads();
    float acc = 0.f;
    for (int k = 0; k < c; ++k)
        acc += w_lds[k] * hw[(size_t)i_lds[k] * H + tid];
    float o = acc * inv + bias[tid];
    if (do_relu) o = fmaxf(o, 0.f);
    hout[(size_t)j * H + tid] = o;
}

// ---------- residual + layernorm + selector + sigmoid + mask ----------
__global__ void k_final(const float* __restrict__ x, const float* __restrict__ h,
                        const int* __restrict__ mask,
                        const float* __restrict__ selW, const float* __restrict__ selb,
                        const int* __restrict__ t_ts, const int* __restrict__ t_tot,
                        float* __restrict__ out) {
    __shared__ float sm[256];
    int n = blockIdx.x, tid = threadIdx.x;
    float v = x[(size_t)n * H + tid] + h[(size_t)n * H + tid];
    float mean = block_reduce_sum(v, sm) * (1.f / H);
    float d = v - mean;
    float var = block_reduce_sum(d * d, sm) * (1.f / H);
    float xn = d * rsqrtf(var + 1e-5f);
    float dot = block_reduce_sum(xn * selW[tid], sm);
    if (tid == 0) {
        float tctx = (float)t_ts[0] / (float)t_tot[0];
        float logit = dot + tctx * selW[H] + selb[0];
        float s = 1.f / (1.f + __expf(-logit));
        out[n] = mask[n] ? s : 0.f;
    }
}

extern "C" void kernel_launch(void* const* d_in, const int* in_sizes, int n_in,
                              void* d_out, int out_size, void* d_ws, size_t ws_size,
                              hipStream_t stream) {
    const float* adj       = (const float*)d_in[0];
    const float* arrival   = (const float*)d_in[1];
    const float* departure = (const float*)d_in[2];
    const float* hard      = (const float*)d_in[3];
    const int*   mask      = (const int*)d_in[4];
    const float* embW1     = (const float*)d_in[5];
    const float* embb1     = (const float*)d_in[6];
    const float* embW2     = (const float*)d_in[7];
    const float* embb2     = (const float*)d_in[8];
    const float* gatW      = (const float*)d_in[9];
    const float* gatasrc   = (const float*)d_in[10];
    const float* gatadst   = (const float*)d_in[11];
    const float* gatbias   = (const float*)d_in[12];
    const float* selW      = (const float*)d_in[13];
    const float* selb      = (const float*)d_in[14];
    const int*   ts        = (const int*)d_in[15];
    const int*   tot       = (const int*)d_in[16];
    float* out = (float*)d_out;

    float* ws  = (float*)d_ws;
    float* x   = ws;
    float* h   = x  + (size_t)N * H;
    float* hw  = h  + (size_t)N * H;
    float* a_s = hw + (size_t)N * H;
    float* a_d = a_s + N;
    int*   cnt   = (int*)(a_d + N);
    int*   edges = cnt + N;

    k_init_edges<<<N / 256, 256, 0, stream>>>(cnt, edges);
    k_build_edges<<<N, 256, 0, stream>>>(adj, mask, cnt, edges);
    k_embed<<<N / NPB, 256, 0, stream>>>(arrival, departure, hard,
                                         embW1, embb1, embW2, embb2, ts, x);
    for (int l = 0; l < LAYERS; ++l) {
        const float* hin = (l == 0) ? x : h;
        k_matmul<<<N / NPB, 256, 0, stream>>>(hin, gatW + (size_t)l * H * H, hw);
        k_scores<<<N, 256, 0, stream>>>(hw, gatasrc + l * H, gatadst + l * H, a_s, a_d);
        k_aggregate<<<N, 256, 0, stream>>>(hw, a_s, a_d, cnt, edges,
                                           gatbias + l * H, h, l < LAYERS - 1 ? 1 : 0);
    }
    k_final<<<N, 256, 0, stream>>>(x, h, mask, selW, selb, ts, tot, out);
}

// Round 17
// 189.811 us; speedup vs baseline: 1.0900x; 1.0900x over previous
//
#include <hip/hip_runtime.h>
#define N 4096
#define H 256
#define CAP 128
#define NPB 16

__device__ __forceinline__ float brs(float v, float* s4) {
    int ln = threadIdx.x & 63, wv = threadIdx.x >> 6;
#pragma unroll
    for (int o = 32; o; o >>= 1) v += __shfl_xor(v, o, 64);
    if (ln == 0) s4[wv] = v;
    __syncthreads();
    float r = s4[0] + s4[1] + s4[2] + s4[3];
    __syncthreads();
    return r;
}

__device__ __forceinline__ float brm(float v, float* s4) {
    int ln = threadIdx.x & 63, wv = threadIdx.x >> 6;
#pragma unroll
    for (int o = 32; o; o >>= 1) v = fmaxf(v, __shfl_xor(v, o, 64));
    if (ln == 0) s4[wv] = v;
    __syncthreads();
    float r = fmaxf(fmaxf(s4[0], s4[1]), fmaxf(s4[2], s4[3]));
    __syncthreads();
    return r;
}

__global__ void k_init(int* cnt, int* eg) {
    int j = blockIdx.x * blockDim.x + threadIdx.x;
    if (j < N) { cnt[j] = 1; eg[j * CAP] = j; }
}

__global__ void k_edges(const float* __restrict__ adj, const int* __restrict__ mask,
                        int* cnt, int* eg) {
    int i = blockIdx.x;
    if (!mask[i]) return;
    const float4* row = (const float4*)(adj + (size_t)i * N);
    int tid = threadIdx.x;
    for (int it = 0; it < 4; ++it) {
        int j4 = it * 256 + tid;
        float4 v = row[j4];
        if (v.x == 0.f && v.y == 0.f && v.z == 0.f && v.w == 0.f) continue;
        int j = j4 * 4;
        if (v.x != 0.f && j     != i && mask[j    ]) { int s = atomicAdd(&cnt[j    ], 1); if (s < CAP) eg[(size_t)(j    ) * CAP + s] = i; }
        if (v.y != 0.f && j + 1 != i && mask[j + 1]) { int s = atomicAdd(&cnt[j + 1], 1); if (s < CAP) eg[(size_t)(j + 1) * CAP + s] = i; }
        if (v.z != 0.f && j + 2 != i && mask[j + 2]) { int s = atomicAdd(&cnt[j + 2], 1); if (s < CAP) eg[(size_t)(j + 2) * CAP + s] = i; }
        if (v.w != 0.f && j + 3 != i && mask[j + 3]) { int s = atomicAdd(&cnt[j + 3], 1); if (s < CAP) eg[(size_t)(j + 3) * CAP + s] = i; }
    }
}

__global__ void k_embed(const float* __restrict__ ar, const float* __restrict__ dp,
                        const float* __restrict__ hd,
                        const float* __restrict__ W1, const float* __restrict__ b1,
                        const float* __restrict__ W2, const float* __restrict__ b2,
                        const int* __restrict__ tts, float* __restrict__ x) {
    __shared__ float A[H * NPB];
    int tid = threadIdx.x, base = blockIdx.x * NPB;
    float ts = (float)tts[0];
    for (int idx = tid; idx < NPB * H; idx += 256) {
        int hh = idx >> 4, p = idx & (NPB - 1);
        int n = base + p;
        float den = dp[n] - ar[n];
        if (den == 0.f) den = 1.f;
        A[idx] = ((ts - ar[n]) / den) * W1[hh] + hd[n] * W1[H + hh] + b1[hh];
    }
    __syncthreads();
    float acc[NPB];
#pragma unroll
    for (int p = 0; p < NPB; ++p) acc[p] = 0.f;
    for (int hh = 0; hh < H; ++hh) {
        float w = W2[(size_t)hh * H + tid];
        const float4* t4 = (const float4*)(A + hh * NPB);
#pragma unroll
        for (int q = 0; q < 4; ++q) {
            float4 a = t4[q];
            acc[q*4+0] += a.x * w; acc[q*4+1] += a.y * w;
            acc[q*4+2] += a.z * w; acc[q*4+3] += a.w * w;
        }
    }
#pragma unroll
    for (int p = 0; p < NPB; ++p)
        x[(size_t)(base + p) * H + tid] = acc[p] + b2[tid];
}

__global__ void k_mm(const float* __restrict__ hin, const float* __restrict__ W,
                     const float* __restrict__ as_, const float* __restrict__ ad_,
                     float* __restrict__ hw, float* __restrict__ sa, float* __restrict__ sd) {
    __shared__ float A[H * NPB];
    int tid = threadIdx.x, base = blockIdx.x * NPB;
    for (int idx = tid; idx < NPB * H; idx += 256) {
        int p = idx >> 8, hh = idx & (H - 1);
        A[hh * NPB + p] = hin[(size_t)(base + p) * H + hh];
    }
    __syncthreads();
    float acc[NPB];
#pragma unroll
    for (int p = 0; p < NPB; ++p) acc[p] = 0.f;
    for (int hh = 0; hh < H; ++hh) {
        float w = W[(size_t)hh * H + tid];
        const float4* t4 = (const float4*)(A + hh * NPB);
#pragma unroll
        for (int q = 0; q < 4; ++q) {
            float4 a = t4[q];
            acc[q*4+0] += a.x * w; acc[q*4+1] += a.y * w;
            acc[q*4+2] += a.z * w; acc[q*4+3] += a.w * w;
        }
    }
#pragma unroll
    for (int p = 0; p < NPB; ++p) hw[(size_t)(base + p) * H + tid] = acc[p];
    __syncthreads();
#pragma unroll
    for (int p = 0; p < NPB; ++p) A[p * H + tid] = acc[p];
    __syncthreads();
    int wv = tid >> 6, ln = tid & 63;
    for (int p = wv; p < NPB; p += 4) {
        float v1 = 0.f, v2 = 0.f;
#pragma unroll
        for (int q = 0; q < 4; ++q) {
            float t = A[p * H + ln + 64 * q];
            v1 += t * as_[ln + 64 * q];
            v2 += t * ad_[ln + 64 * q];
        }
#pragma unroll
        for (int o = 32; o; o >>= 1) {
            v1 += __shfl_xor(v1, o, 64);
            v2 += __shfl_xor(v2, o, 64);
        }
        if (ln == 0) { sa[base + p] = v1; sd[base + p] = v2; }
    }
}

__global__ void k_agg(const float* __restrict__ hw, const float* __restrict__ sa,
                      const float* __restrict__ sd, const int* __restrict__ cnt,
                      const int* __restrict__ eg, const float* __restrict__ bias,
                      float* __restrict__ hout, int relu, int fin,
                      const float* __restrict__ x, const int* __restrict__ mask,
                      const float* __restrict__ sW, const float* __restrict__ sb,
                      const int* __restrict__ tts, const int* __restrict__ ttot,
                      float* __restrict__ out) {
    __shared__ float s4[4];
    __shared__ float wl[CAP];
    __shared__ int il[CAP];
    int j = blockIdx.x, tid = threadIdx.x;
    int c = cnt[j];
    if (c > CAP) c = CAP;
    float e = -INFINITY;
    if (tid < c) {
        int i = eg[(size_t)j * CAP + tid];
        il[tid] = i;
        float v = sa[i] + sd[j];
        e = (v > 0.f) ? v : 0.2f * v;
    }
    float m = brm(e, s4);
    float w = 0.f;
    if (tid < c) { w = __expf(e - m); wl[tid] = w; }
    float inv = 1.f / brs(w, s4);
    __syncthreads();
    float acc = 0.f;
    for (int k = 0; k < c; ++k)
        acc += wl[k] * hw[(size_t)il[k] * H + tid];
    float o = acc * inv + bias[tid];
    if (!fin) {
        if (relu) o = fmaxf(o, 0.f);
        hout[(size_t)j * H + tid] = o;
    } else {
        float v = x[(size_t)j * H + tid] + o;
        float mn = brs(v, s4) * (1.f / H);
        float d = v - mn;
        float vr = brs(d * d, s4) * (1.f / H);
        float xn = d * rsqrtf(vr + 1e-5f);
        float dot = brs(xn * sW[tid], s4);
        if (tid == 0) {
            float lg = dot + ((float)tts[0] / (float)ttot[0]) * sW[H] + sb[0];
            out[j] = mask[j] ? 1.f / (1.f + __expf(-lg)) : 0.f;
        }
    }
}

extern "C" void kernel_launch(void* const* d_in, const int* in_sizes, int n_in,
                              void* d_out, int out_size, void* d_ws, size_t ws_size,
                              hipStream_t stream) {
    const float* adj = (const float*)d_in[0];
    const float* ar  = (const float*)d_in[1];
    const float* dp  = (const float*)d_in[2];
    const float* hd  = (const float*)d_in[3];
    const int*   mk  = (const int*)d_in[4];
    const float* eW1 = (const float*)d_in[5];
    const float* eb1 = (const float*)d_in[6];
    const float* eW2 = (const float*)d_in[7];
    const float* eb2 = (const float*)d_in[8];
    const float* gW  = (const float*)d_in[9];
    const float* gas = (const float*)d_in[10];
    const float* gad = (const float*)d_in[11];
    const float* gb  = (const float*)d_in[12];
    const float* sW  = (const float*)d_in[13];
    const float* sb  = (const float*)d_in[14];
    const int*   ts  = (const int*)d_in[15];
    const int*   tt  = (const int*)d_in[16];
    float* out = (float*)d_out;

    float* ws  = (float*)d_ws;
    float* x   = ws;
    float* h   = x  + (size_t)N * H;
    float* hw  = h  + (size_t)N * H;
    float* sa  = hw + (size_t)N * H;
    float* sd  = sa + N;
    int*   cnt = (int*)(sd + N);
    int*   eg  = cnt + N;

    k_init<<<N / 256, 256, 0, stream>>>(cnt, eg);
    k_edges<<<N, 256, 0, stream>>>(adj, mk, cnt, eg);
    k_embed<<<N / NPB, 256, 0, stream>>>(ar, dp, hd, eW1, eb1, eW2, eb2, ts, x);
    for (int l = 0; l < 3; ++l) {
        int last = (l == 2);
        k_mm<<<N / NPB, 256, 0, stream>>>((l == 0) ? x : h, gW + (size_t)l * H * H,
                                          gas + (size_t)l * H, gad + (size_t)l * H,
                                          hw, sa, sd);
        k_agg<<<N, 256, 0, stream>>>(hw, sa, sd, cnt, eg, gb + (size_t)l * H, h,
                                     !last, last, x, mk, sW, sb, ts, tt, out);
    }
}